// Round 4
// baseline (413.906 us; speedup 1.0000x reference)
//
#include <hip/hip_runtime.h>
#include <hip/hip_bf16.h>
#include <math.h>

#define S_LEN 2048
#define HID 3072
#define NHEAD 32
#define NKV 8
#define HDIM 96
#define QKV_N 4608   // 32*96 + 2*8*96
#define NB 32        // S/64 blocks
#define GHDIM 128

typedef __attribute__((ext_vector_type(8))) short bf16x8;
typedef __attribute__((ext_vector_type(4))) float f32x4;
typedef unsigned short ushort_t;

// 1/sqrt(96) * log2(e): Q pre-scaled so softmax runs in exp2 domain
#define SCALE2 0.14724444754f

__device__ __forceinline__ unsigned short f2bf(float x) {
    unsigned u = __float_as_uint(x);
    u += 0x7fffu + ((u >> 16) & 1u);
    return (unsigned short)(u >> 16);
}
__device__ __forceinline__ unsigned packbf2(float a, float b) {
    return (unsigned)f2bf(a) | ((unsigned)f2bf(b) << 16);
}

#define GLOBAL_AS __attribute__((address_space(1)))
#define LDS_AS __attribute__((address_space(3)))
// async global->LDS, 16B per lane; lds dest = wave-uniform base + lane*16
__device__ __forceinline__ void gl_lds16(const void* g, void* l) {
    __builtin_amdgcn_global_load_lds((const GLOBAL_AS unsigned int*)g,
                                     (LDS_AS unsigned int*)l, 16, 0, 0);
}
// raw barrier (no implicit vmcnt(0) drain) with compiler code-motion fence
__device__ __forceinline__ void barrier_raw() {
    asm volatile("s_barrier" ::: "memory");
}

// ============ bf16 MFMA GEMM (m97 structure): C_f32[M,N] = A[M,K] @ Bt[N,K]^T
__global__ __launch_bounds__(256, 2) void gemm_bf16(const ushort_t* __restrict__ A,
                                                    const ushort_t* __restrict__ Bt,
                                                    float* __restrict__ C,
                                                    int M, int N, int K) {
    __shared__ ushort_t As[128 * 64];
    __shared__ ushort_t Bs[128 * 64];
    const int tid = threadIdx.x;
    const int lane = tid & 63;
    const int w = tid >> 6;
    const int wm = (w >> 1) * 64;
    const int wn = (w & 1) * 64;
    const int l15 = lane & 15;
    const int quad = lane >> 4;
    const int m0 = blockIdx.y * 128;
    const int n0 = blockIdx.x * 128;

    f32x4 acc[4][4] = {};

    for (int k0 = 0; k0 < K; k0 += 64) {
        __syncthreads();
#pragma unroll
        for (int j = 0; j < 4; ++j) {
            int s = j * 256 + w * 64 + lane;
            int row = s >> 3;
            int kc = (s & 7) ^ (row & 7);
            gl_lds16(A + (size_t)(m0 + row) * K + k0 + kc * 8,
                     &As[(j * 256 + w * 64) * 8]);
        }
#pragma unroll
        for (int j = 0; j < 4; ++j) {
            int s = j * 256 + w * 64 + lane;
            int row = s >> 3;
            int kc = (s & 7) ^ (row & 7);
            gl_lds16(Bt + (size_t)(n0 + row) * K + k0 + kc * 8,
                     &Bs[(j * 256 + w * 64) * 8]);
        }
        __syncthreads();
        bf16x8 af[2][4], bf[2][4];
#pragma unroll
        for (int mt = 0; mt < 4; ++mt) {
            int row = wm + mt * 16 + l15;
            int rx = row & 7;
#pragma unroll
            for (int ph = 0; ph < 2; ++ph)
                af[ph][mt] = *(const bf16x8*)&As[(row * 8 + ((ph * 4 + quad) ^ rx)) * 8];
        }
#pragma unroll
        for (int nt = 0; nt < 4; ++nt) {
            int row = wn + nt * 16 + l15;
            int rx = row & 7;
#pragma unroll
            for (int ph = 0; ph < 2; ++ph)
                bf[ph][nt] = *(const bf16x8*)&Bs[(row * 8 + ((ph * 4 + quad) ^ rx)) * 8];
        }
#pragma unroll
        for (int ph = 0; ph < 2; ++ph)
#pragma unroll
            for (int mt = 0; mt < 4; ++mt)
#pragma unroll
                for (int nt = 0; nt < 4; ++nt)
                    acc[mt][nt] = __builtin_amdgcn_mfma_f32_16x16x32_bf16(
                        af[ph][mt], bf[ph][nt], acc[mt][nt], 0, 0, 0);
    }
#pragma unroll
    for (int mt = 0; mt < 4; ++mt)
#pragma unroll
        for (int nt = 0; nt < 4; ++nt)
#pragma unroll
            for (int r = 0; r < 4; ++r) {
                int row = m0 + wm + mt * 16 + quad * 4 + r;
                int col = n0 + wn + nt * 16 + l15;
                C[(size_t)row * N + col] = acc[mt][nt][r];
            }
}

// ---------------- fp32 -> bf16 elementwise convert ----------------------------
__global__ __launch_bounds__(256) void conv_bf16(const float* __restrict__ X,
                                                 ushort_t* __restrict__ Y, int n4) {
    int i = blockIdx.x * 256 + threadIdx.x;
    if (i >= n4) return;
    const float4 v = *(const float4*)(X + (size_t)i * 4);
    int2 p;
    p.x = (int)packbf2(v.x, v.y);
    p.y = (int)packbf2(v.z, v.w);
    *(int2*)(Y + (size_t)i * 4) = p;
}

// ---------------- W f32 [K][N] -> Wt bf16 [N][K] (tiled 64x64) ---------------
__global__ __launch_bounds__(256) void transpose_convert(const float* __restrict__ W,
                                                         ushort_t* __restrict__ Wt,
                                                         int K, int N) {
    __shared__ float Ts[64][65];
    const int k0 = blockIdx.y * 64, n0 = blockIdx.x * 64;
    const int tid = threadIdx.x;
    {
        int r = tid >> 2, cq = tid & 3;
#pragma unroll
        for (int i = 0; i < 4; ++i) {
            int c = cq * 16 + i * 4;
            const float4 v = *(const float4*)(W + (size_t)(k0 + r) * N + n0 + c);
            Ts[r][c] = v.x; Ts[r][c + 1] = v.y; Ts[r][c + 2] = v.z; Ts[r][c + 3] = v.w;
        }
    }
    __syncthreads();
#pragma unroll
    for (int it = 0; it < 2; ++it) {
        int n = (tid >> 3) + it * 32;
        int kc = tid & 7;
        int4 r;
        r.x = (int)(packbf2(Ts[kc * 8 + 0][n], Ts[kc * 8 + 1][n]));
        r.y = (int)(packbf2(Ts[kc * 8 + 2][n], Ts[kc * 8 + 3][n]));
        r.z = (int)(packbf2(Ts[kc * 8 + 4][n], Ts[kc * 8 + 5][n]));
        r.w = (int)(packbf2(Ts[kc * 8 + 6][n], Ts[kc * 8 + 7][n]));
        *(int4*)(Wt + (size_t)(n0 + n) * K + k0 + kc * 8) = r;
    }
}

// ---------------- k pooling (mean+max over 64 tokens, pre-RoPE) + gate GEMV ---
__global__ __launch_bounds__(128) void pool_gate_k_kernel(const float* __restrict__ qkv,
                                                          const float* __restrict__ gate_wk,
                                                          float* __restrict__ k_gate) {
    int nb = blockIdx.x, h = blockIdx.y;
    int tid = threadIdx.x;
    __shared__ float pool[192];
    if (tid < 96) {
        float s = 0.f, mx = -1e30f;
        for (int i = 0; i < 64; i++) {
            float v = qkv[(size_t)(nb * 64 + i) * QKV_N + HID + h * 96 + tid];
            s += v;
            mx = fmaxf(mx, v);
        }
        pool[tid] = s * (1.f / 64.f);
        pool[96 + tid] = mx;
    }
    __syncthreads();
    float acc = 0.f;
    for (int e = 0; e < 192; e++) acc += pool[e] * gate_wk[e * GHDIM + tid];
    k_gate[(size_t)(nb * NKV + h) * GHDIM + tid] = acc;
}

// ---------------- q pooling (mean over 4 heads x 64 tokens, pre-RoPE) + gate --
__global__ __launch_bounds__(128) void pool_gate_q_kernel(const float* __restrict__ qkv,
                                                          const float* __restrict__ gate_wq,
                                                          float* __restrict__ q_gate) {
    int nb = blockIdx.x, h = blockIdx.y;
    int tid = threadIdx.x;
    __shared__ float pool[96];
    if (tid < 96) {
        float s = 0.f;
        for (int i = 0; i < 64; i++)
            for (int g = 0; g < 4; g++)
                s += qkv[(size_t)(nb * 64 + i) * QKV_N + (h * 4 + g) * 96 + tid];
        pool[tid] = s * (1.f / 256.f);
    }
    __syncthreads();
    float acc = 0.f;
    for (int e = 0; e < 96; e++) acc += pool[e] * gate_wq[e * GHDIM + tid];
    q_gate[(size_t)(nb * NKV + h) * GHDIM + tid] = acc;
}

// ---------------- block gate logits -> softmax -> threshold mask --------------
__global__ __launch_bounds__(64) void blockmask_kernel(const float* __restrict__ q_gate,
                                                       const float* __restrict__ k_gate,
                                                       int* __restrict__ mask) {
    int h = blockIdx.x, qb = blockIdx.y;
    int tid = threadIdx.x;
    __shared__ float logits[32];
    if (tid < 32) {
        if (tid <= qb) {
            float acc = 0.f;
            const float* qg = &q_gate[(size_t)(qb * NKV + h) * GHDIM];
            const float* kg = &k_gate[(size_t)(tid * NKV + h) * GHDIM];
            for (int e = 0; e < GHDIM; e++) acc += qg[e] * kg[e];
            logits[tid] = acc * 0.08838834764831845f;
        } else {
            logits[tid] = -1e30f;
        }
    }
    __syncthreads();
    if (tid < 32) {
        float mx = -1e30f;
        for (int j = 0; j <= qb; j++) mx = fmaxf(mx, logits[j]);
        float sum = 0.f;
        for (int j = 0; j <= qb; j++) sum += __expf(logits[j] - mx);
        float p = (tid <= qb) ? __expf(logits[tid] - mx) / sum : 0.f;
        int m = ((p >= 0.03f) && (tid <= qb)) || (tid == qb);
        mask[(h * NB + qb) * NB + tid] = m;
    }
}

// ---------------- fused RoPE: q -> Qb bf16 (pre-scaled), k -> Kb bf16 [h][s][96]
__global__ __launch_bounds__(256) void rope_qk_kernel(const float* __restrict__ qkv,
                                                      const float* __restrict__ cosb,
                                                      const float* __restrict__ sinb,
                                                      ushort_t* __restrict__ Qb,
                                                      ushort_t* __restrict__ Kb) {
    int idx = blockIdx.x * 256 + threadIdx.x;  // total S*40*48
    int d = idx % 48;
    int tmp = idx / 48;
    int head = tmp % 40;
    int s = tmp / 40;
    float c0 = cosb[s * 96 + d], c1 = cosb[s * 96 + d + 48];
    float s0 = sinb[s * 96 + d], s1 = sinb[s * 96 + d + 48];
    if (head < 32) {
        size_t base = (size_t)s * QKV_N + head * 96;
        float x0 = qkv[base + d], x1 = qkv[base + d + 48];
        size_t ob = (size_t)s * HID + head * 96;
        Qb[ob + d] = f2bf((x0 * c0 - x1 * s0) * SCALE2);
        Qb[ob + d + 48] = f2bf((x1 * c1 + x0 * s1) * SCALE2);
    } else {
        int hh = head - 32;
        size_t base = (size_t)s * QKV_N + HID + hh * 96;
        float x0 = qkv[base + d], x1 = qkv[base + d + 48];
        size_t ob = ((size_t)hh * S_LEN + s) * 96;
        Kb[ob + d] = f2bf(x0 * c0 - x1 * s0);
        Kb[ob + d + 48] = f2bf(x1 * c1 + x0 * s1);
    }
}

// ---------------- V transpose -> Vtb bf16 [NKV][96][S] ------------------------
__global__ __launch_bounds__(256) void transpose_v_kernel(const float* __restrict__ qkv,
                                                          ushort_t* __restrict__ Vtb) {
    __shared__ float Vs[64][97];
    const int ibk = blockIdx.x, h = blockIdx.y;
    const int tid = threadIdx.x;
    {
        int t = tid >> 2, cq = tid & 3;
#pragma unroll
        for (int i = 0; i < 6; ++i) {
            int c = cq * 24 + i * 4;
            const float4 v = *(const float4*)(qkv + (size_t)(ibk * 64 + t) * QKV_N +
                                              HID + 768 + h * 96 + c);
            Vs[t][c] = v.x; Vs[t][c + 1] = v.y; Vs[t][c + 2] = v.z; Vs[t][c + 3] = v.w;
        }
    }
    __syncthreads();
#pragma unroll
    for (int it = 0; it < 3; ++it) {
        int s = tid + it * 256;
        int d = s >> 3, tc = s & 7;
        int4 r;
        r.x = (int)(packbf2(Vs[tc * 8 + 0][d], Vs[tc * 8 + 1][d]));
        r.y = (int)(packbf2(Vs[tc * 8 + 2][d], Vs[tc * 8 + 3][d]));
        r.z = (int)(packbf2(Vs[tc * 8 + 4][d], Vs[tc * 8 + 5][d]));
        r.w = (int)(packbf2(Vs[tc * 8 + 6][d], Vs[tc * 8 + 7][d]));
        *(int4*)(Vtb + ((size_t)h * 96 + d) * S_LEN + ibk * 64 + tc * 8) = r;
    }
}

// ============ MFMA block-sparse flash attention, async double-buffered ========
// grid (NHEAD, NB) with ib reversed (heavy blocks first). 4 waves/block.
// Raw s_barrier + manual vmcnt(6): next tile's K/V loads stay in flight
// across the barrier (AITER-style; __syncthreads would drain vmcnt to 0).
__global__ __launch_bounds__(256) void attn_mfma(const ushort_t* __restrict__ Qb,
                                                 const ushort_t* __restrict__ Kb,
                                                 const ushort_t* __restrict__ Vtb,
                                                 const int* __restrict__ mask,
                                                 ushort_t* __restrict__ out) {
    const int hq = blockIdx.x;
    const int ib = NB - 1 - (int)blockIdx.y;
    const int h = hq >> 2;
    const int tid = threadIdx.x;
    const int lane = tid & 63;
    const int w = tid >> 6;
    const int l15 = lane & 15;
    const int quad = lane >> 4;

    __shared__ ushort_t KsL[2][64 * 96];  // [t][12 chunks, rotated by t&7]
    __shared__ ushort_t VtL[2][96 * 64];  // [d][8 chunks, xor d&7]
    __shared__ ushort_t Ps[64][72];

    // K-read chunk positions: p = (c + (t&7)) % 12, c = ks*4+quad, t&7 = l15&7
    int pk[3];
    {
        int b0 = quad + (l15 & 7);
#pragma unroll
        for (int ks = 0; ks < 3; ++ks) {
            int p = b0 + ks * 4;
            if (p >= 12) p -= 12;
            if (p >= 12) p -= 12;
            pk[ks] = p;
        }
    }

    bf16x8 qf[3];
    {
        const ushort_t* qp = Qb + (size_t)(ib * 64 + w * 16 + l15) * HID + hq * 96;
#pragma unroll
        for (int ks = 0; ks < 3; ++ks)
            qf[ks] = *(const bf16x8*)(qp + ks * 32 + quad * 8);
    }

    const ushort_t* kbase = Kb + (size_t)h * S_LEN * 96;
    const ushort_t* vbase = Vtb + (size_t)h * 96 * S_LEN;

    // active-jb bitmask (wave-uniform; diag guaranteed set)
    unsigned long long bits =
        __ballot((lane <= ib) && (mask[(h * NB + ib) * NB + (lane & 31)] != 0));

    float m_i[4], l_i[4];
#pragma unroll
    for (int r = 0; r < 4; ++r) { m_i[r] = -1e30f; l_i[r] = 0.f; }
    f32x4 acc_o[6] = {};

    auto stage = [&](int jb, int buf) {
        // K: 768 chunks (64 rows x 12), rotation swizzle
#pragma unroll
        for (int j = 0; j < 3; ++j) {
            int s = j * 256 + w * 64 + lane;
            int t = (s * 2731) >> 15;       // s / 12
            int cpos = s - t * 12;
            int c = cpos - (t & 7);
            if (c < 0) c += 12;
            gl_lds16(kbase + (size_t)(jb * 64 + t) * 96 + c * 8,
                     &KsL[buf][(j * 256 + w * 64) * 8]);
        }
        // V: 768 chunks (96 rows x 8), xor swizzle
#pragma unroll
        for (int j = 0; j < 3; ++j) {
            int s = j * 256 + w * 64 + lane;
            int d = s >> 3;
            int tc = (s & 7) ^ (d & 7);
            gl_lds16(vbase + (size_t)d * S_LEN + jb * 64 + tc * 8,
                     &VtL[buf][(j * 256 + w * 64) * 8]);
        }
    };

    int jb = (int)__builtin_ctzll(bits);
    bits &= bits - 1;
    stage(jb, 0);
    int cur = 0;

    while (true) {
        int jn = -1;
        if (bits) {
            jn = (int)__builtin_ctzll(bits);
            bits &= bits - 1;
        }
        if (jn >= 0) {
            stage(jn, cur ^ 1);
            asm volatile("s_waitcnt vmcnt(6)" ::: "memory");  // cur's 6 loads done
        } else {
            asm volatile("s_waitcnt vmcnt(0)" ::: "memory");
        }
        barrier_raw();

        const ushort_t* Kc = KsL[cur];
        const ushort_t* Vc = VtL[cur];

        // QK^T (Q pre-scaled by 1/sqrt(96)*log2e -> logits in exp2 domain)
        f32x4 s4[4] = {};
#pragma unroll
        for (int ks = 0; ks < 3; ++ks)
#pragma unroll
            for (int nt = 0; nt < 4; ++nt) {
                bf16x8 kb = *(const bf16x8*)&Kc[(nt * 16 + l15) * 96 + pk[ks] * 8];
                s4[nt] = __builtin_amdgcn_mfma_f32_16x16x32_bf16(qf[ks], kb, s4[nt], 0, 0, 0);
            }
        if (jb == ib) {
#pragma unroll
            for (int nt = 0; nt < 4; ++nt)
#pragma unroll
                for (int r = 0; r < 4; ++r)
                    if ((nt * 16 + l15) > (w * 16 + quad * 4 + r)) s4[nt][r] = -1e30f;
        }
        float alpha[4];
#pragma unroll
        for (int r = 0; r < 4; ++r) {
            float mx = fmaxf(fmaxf(s4[0][r], s4[1][r]), fmaxf(s4[2][r], s4[3][r]));
            mx = fmaxf(mx, __shfl_xor(mx, 1));
            mx = fmaxf(mx, __shfl_xor(mx, 2));
            mx = fmaxf(mx, __shfl_xor(mx, 4));
            mx = fmaxf(mx, __shfl_xor(mx, 8));
            float mnew = fmaxf(m_i[r], mx);
            alpha[r] = __builtin_amdgcn_exp2f(m_i[r] - mnew);
            float ps = 0.f;
#pragma unroll
            for (int nt = 0; nt < 4; ++nt) {
                float p = __builtin_amdgcn_exp2f(s4[nt][r] - mnew);
                s4[nt][r] = p;
                ps += p;
            }
            ps += __shfl_xor(ps, 1);
            ps += __shfl_xor(ps, 2);
            ps += __shfl_xor(ps, 4);
            ps += __shfl_xor(ps, 8);
            l_i[r] = l_i[r] * alpha[r] + ps;
            m_i[r] = mnew;
        }
#pragma unroll
        for (int t = 0; t < 6; ++t)
#pragma unroll
            for (int r = 0; r < 4; ++r) acc_o[t][r] *= alpha[r];
        // P round-trip: C-layout regs -> LDS -> A-layout frags (per-wave strip)
#pragma unroll
        for (int nt = 0; nt < 4; ++nt)
#pragma unroll
            for (int r = 0; r < 4; ++r)
                Ps[w * 16 + quad * 4 + r][nt * 16 + l15] = (short)f2bf(s4[nt][r]);
#pragma unroll
        for (int ks = 0; ks < 2; ++ks) {
            bf16x8 pa = *(const bf16x8*)&Ps[w * 16 + l15][ks * 32 + quad * 8];
#pragma unroll
            for (int t = 0; t < 6; ++t) {
                int d = t * 16 + l15;
                int slot = (ks * 4 + quad) ^ (d & 7);
                bf16x8 vb = *(const bf16x8*)&Vc[(d * 8 + slot) * 8];
                acc_o[t] = __builtin_amdgcn_mfma_f32_16x16x32_bf16(pa, vb, acc_o[t], 0, 0, 0);
            }
        }

        if (jn < 0) break;
        // all waves done reading buf[cur] before next iteration overwrites it
        asm volatile("s_waitcnt lgkmcnt(0)" ::: "memory");
        barrier_raw();
        jb = jn;
        cur ^= 1;
    }

#pragma unroll
    for (int r = 0; r < 4; ++r) {
        float inv = 1.f / l_i[r];
        int row = ib * 64 + w * 16 + quad * 4 + r;
#pragma unroll
        for (int t = 0; t < 6; ++t)
            out[(size_t)row * HID + hq * 96 + t * 16 + l15] = f2bf(acc_o[t][r] * inv);
    }
}

extern "C" void kernel_launch(void* const* d_in, const int* in_sizes, int n_in,
                              void* d_out, int out_size, void* d_ws, size_t ws_size,
                              hipStream_t stream) {
    const float* hidden  = (const float*)d_in[0];
    const float* cosb    = (const float*)d_in[1];
    const float* sinb    = (const float*)d_in[2];
    const float* qkv_w   = (const float*)d_in[3];
    const float* o_w     = (const float*)d_in[4];
    const float* gate_wq = (const float*)d_in[5];
    const float* gate_wk = (const float*)d_in[6];
    float* out = (float*)d_out;

    char* ws = (char*)d_ws;
    float*    qkv   = (float*)ws;                          // 37,748,736 B
    ushort_t* h_bf  = (ushort_t*)(ws + 37748736);          // 12,582,912 B (reused as Qb)
    ushort_t* w1t   = (ushort_t*)(ws + 50331648);          // 28,311,552 B
    ushort_t* attn_out = (ushort_t*)(ws + 78643200);       // 12,582,912 B
    ushort_t* Kb    = (ushort_t*)(ws + 91226112);          //  3,145,728 B
    ushort_t* Vtb   = (ushort_t*)(ws + 95420416);          //  3,145,728 B
    float* k_gate   = (float*)(ws + 98566144);
    float* q_gate   = (float*)(ws + 98697216);
    int*   mask     = (int*)(ws + 98828288);
    ushort_t* Qb    = h_bf;              // alias: h_bf dead after gemm1
    ushort_t* o_wt  = (ushort_t*)qkv;    // alias: qkv dead after rope/transpose_v

    // prep for QKV GEMM
    conv_bf16<<<(S_LEN * HID / 4 + 255) / 256, 256, 0, stream>>>(hidden, h_bf, S_LEN * HID / 4);
    transpose_convert<<<dim3(QKV_N / 64, HID / 64), 256, 0, stream>>>(qkv_w, w1t, HID, QKV_N);
    // 1. QKV projection -> f32 qkv
    gemm_bf16<<<dim3(QKV_N / 128, S_LEN / 128), 256, 0, stream>>>(h_bf, w1t, qkv, S_LEN, QKV_N, HID);
    // 2-4. pooled gates + mask (pre-RoPE, fp32)
    pool_gate_k_kernel<<<dim3(NB, NKV), 128, 0, stream>>>(qkv, gate_wk, k_gate);
    pool_gate_q_kernel<<<dim3(NB, NKV), 128, 0, stream>>>(qkv, gate_wq, q_gate);
    blockmask_kernel<<<dim3(NKV, NB), 64, 0, stream>>>(q_gate, k_gate, mask);
    // 5. RoPE + repack to bf16 attention layouts (Q pre-scaled)
    rope_qk_kernel<<<S_LEN * 40 * 48 / 256, 256, 0, stream>>>(qkv, cosb, sinb, Qb, Kb);
    transpose_v_kernel<<<dim3(NB, NKV), 256, 0, stream>>>(qkv, Vtb);
    // prep O-GEMM weights into qkv space (qkv dead now)
    transpose_convert<<<dim3(HID / 64, HID / 64), 256, 0, stream>>>(o_w, o_wt, HID, HID);
    // 6. block-sparse flash attention -> bf16
    attn_mfma<<<dim3(NHEAD, NB), 256, 0, stream>>>(Qb, Kb, Vtb, mask, attn_out);
    // 7. output projection
    gemm_bf16<<<dim3(HID / 128, S_LEN / 128), 256, 0, stream>>>(attn_out, o_wt, out, S_LEN, HID, HID);
}

// Round 5
// 389.194 us; speedup vs baseline: 1.0635x; 1.0635x over previous
//
#include <hip/hip_runtime.h>
#include <hip/hip_bf16.h>
#include <math.h>

#define S_LEN 2048
#define HID 3072
#define NHEAD 32
#define NKV 8
#define HDIM 96
#define QKV_N 4608   // 32*96 + 2*8*96
#define NB 32        // S/64 blocks
#define GHDIM 128

typedef __attribute__((ext_vector_type(8))) short bf16x8;
typedef __attribute__((ext_vector_type(4))) short bf16x4;
typedef __attribute__((ext_vector_type(4))) float f32x4;
typedef unsigned short ushort_t;

// 1/sqrt(96) * log2(e): Q pre-scaled so softmax runs in exp2 domain
#define SCALE2 0.14724444754f

__device__ __forceinline__ unsigned short f2bf(float x) {
    unsigned u = __float_as_uint(x);
    u += 0x7fffu + ((u >> 16) & 1u);
    return (unsigned short)(u >> 16);
}
__device__ __forceinline__ unsigned packbf2(float a, float b) {
    return (unsigned)f2bf(a) | ((unsigned)f2bf(b) << 16);
}

#define GLOBAL_AS __attribute__((address_space(1)))
#define LDS_AS __attribute__((address_space(3)))
// async global->LDS, 16B per lane; lds dest = wave-uniform base + lane*16
__device__ __forceinline__ void gl_lds16(const void* g, void* l) {
    __builtin_amdgcn_global_load_lds((const GLOBAL_AS unsigned int*)g,
                                     (LDS_AS unsigned int*)l, 16, 0, 0);
}
// raw barrier (no implicit vmcnt(0) drain) with compiler code-motion fence
__device__ __forceinline__ void barrier_raw() {
    asm volatile("s_barrier" ::: "memory");
}

// ============ bf16 MFMA GEMM (m97 structure): C_f32[M,N] = A[M,K] @ Bt[N,K]^T
__global__ __launch_bounds__(256, 2) void gemm_bf16(const ushort_t* __restrict__ A,
                                                    const ushort_t* __restrict__ Bt,
                                                    float* __restrict__ C,
                                                    int M, int N, int K) {
    __shared__ ushort_t As[128 * 64];
    __shared__ ushort_t Bs[128 * 64];
    const int tid = threadIdx.x;
    const int lane = tid & 63;
    const int w = tid >> 6;
    const int wm = (w >> 1) * 64;
    const int wn = (w & 1) * 64;
    const int l15 = lane & 15;
    const int quad = lane >> 4;
    const int m0 = blockIdx.y * 128;
    const int n0 = blockIdx.x * 128;

    f32x4 acc[4][4] = {};

    for (int k0 = 0; k0 < K; k0 += 64) {
        __syncthreads();
#pragma unroll
        for (int j = 0; j < 4; ++j) {
            int s = j * 256 + w * 64 + lane;
            int row = s >> 3;
            int kc = (s & 7) ^ (row & 7);
            gl_lds16(A + (size_t)(m0 + row) * K + k0 + kc * 8,
                     &As[(j * 256 + w * 64) * 8]);
        }
#pragma unroll
        for (int j = 0; j < 4; ++j) {
            int s = j * 256 + w * 64 + lane;
            int row = s >> 3;
            int kc = (s & 7) ^ (row & 7);
            gl_lds16(Bt + (size_t)(n0 + row) * K + k0 + kc * 8,
                     &Bs[(j * 256 + w * 64) * 8]);
        }
        __syncthreads();
        bf16x8 af[2][4], bf[2][4];
#pragma unroll
        for (int mt = 0; mt < 4; ++mt) {
            int row = wm + mt * 16 + l15;
            int rx = row & 7;
#pragma unroll
            for (int ph = 0; ph < 2; ++ph)
                af[ph][mt] = *(const bf16x8*)&As[(row * 8 + ((ph * 4 + quad) ^ rx)) * 8];
        }
#pragma unroll
        for (int nt = 0; nt < 4; ++nt) {
            int row = wn + nt * 16 + l15;
            int rx = row & 7;
#pragma unroll
            for (int ph = 0; ph < 2; ++ph)
                bf[ph][nt] = *(const bf16x8*)&Bs[(row * 8 + ((ph * 4 + quad) ^ rx)) * 8];
        }
#pragma unroll
        for (int ph = 0; ph < 2; ++ph)
#pragma unroll
            for (int mt = 0; mt < 4; ++mt)
#pragma unroll
                for (int nt = 0; nt < 4; ++nt)
                    acc[mt][nt] = __builtin_amdgcn_mfma_f32_16x16x32_bf16(
                        af[ph][mt], bf[ph][nt], acc[mt][nt], 0, 0, 0);
    }
#pragma unroll
    for (int mt = 0; mt < 4; ++mt)
#pragma unroll
        for (int nt = 0; nt < 4; ++nt)
#pragma unroll
            for (int r = 0; r < 4; ++r) {
                int row = m0 + wm + mt * 16 + quad * 4 + r;
                int col = n0 + wn + nt * 16 + l15;
                C[(size_t)row * N + col] = acc[mt][nt][r];
            }
}

// ---------------- fp32 -> bf16 elementwise convert ----------------------------
__global__ __launch_bounds__(256) void conv_bf16(const float* __restrict__ X,
                                                 ushort_t* __restrict__ Y, int n4) {
    int i = blockIdx.x * 256 + threadIdx.x;
    if (i >= n4) return;
    const float4 v = *(const float4*)(X + (size_t)i * 4);
    int2 p;
    p.x = (int)packbf2(v.x, v.y);
    p.y = (int)packbf2(v.z, v.w);
    *(int2*)(Y + (size_t)i * 4) = p;
}

// ---------------- W f32 [K][N] -> Wt bf16 [N][K] (tiled 64x64) ---------------
__global__ __launch_bounds__(256) void transpose_convert(const float* __restrict__ W,
                                                         ushort_t* __restrict__ Wt,
                                                         int K, int N) {
    __shared__ float Ts[64][65];
    const int k0 = blockIdx.y * 64, n0 = blockIdx.x * 64;
    const int tid = threadIdx.x;
    {
        int r = tid >> 2, cq = tid & 3;
#pragma unroll
        for (int i = 0; i < 4; ++i) {
            int c = cq * 16 + i * 4;
            const float4 v = *(const float4*)(W + (size_t)(k0 + r) * N + n0 + c);
            Ts[r][c] = v.x; Ts[r][c + 1] = v.y; Ts[r][c + 2] = v.z; Ts[r][c + 3] = v.w;
        }
    }
    __syncthreads();
#pragma unroll
    for (int it = 0; it < 2; ++it) {
        int n = (tid >> 3) + it * 32;
        int kc = tid & 7;
        int4 r;
        r.x = (int)(packbf2(Ts[kc * 8 + 0][n], Ts[kc * 8 + 1][n]));
        r.y = (int)(packbf2(Ts[kc * 8 + 2][n], Ts[kc * 8 + 3][n]));
        r.z = (int)(packbf2(Ts[kc * 8 + 4][n], Ts[kc * 8 + 5][n]));
        r.w = (int)(packbf2(Ts[kc * 8 + 6][n], Ts[kc * 8 + 7][n]));
        *(int4*)(Wt + (size_t)(n0 + n) * K + k0 + kc * 8) = r;
    }
}

// ---------------- k pooling (mean+max over 64 tokens, pre-RoPE) + gate GEMV ---
__global__ __launch_bounds__(128) void pool_gate_k_kernel(const float* __restrict__ qkv,
                                                          const float* __restrict__ gate_wk,
                                                          float* __restrict__ k_gate) {
    int nb = blockIdx.x, h = blockIdx.y;
    int tid = threadIdx.x;
    __shared__ float pool[192];
    if (tid < 96) {
        float s = 0.f, mx = -1e30f;
        for (int i = 0; i < 64; i++) {
            float v = qkv[(size_t)(nb * 64 + i) * QKV_N + HID + h * 96 + tid];
            s += v;
            mx = fmaxf(mx, v);
        }
        pool[tid] = s * (1.f / 64.f);
        pool[96 + tid] = mx;
    }
    __syncthreads();
    float acc = 0.f;
    for (int e = 0; e < 192; e++) acc += pool[e] * gate_wk[e * GHDIM + tid];
    k_gate[(size_t)(nb * NKV + h) * GHDIM + tid] = acc;
}

// ---------------- q pooling (mean over 4 heads x 64 tokens, pre-RoPE) + gate --
__global__ __launch_bounds__(128) void pool_gate_q_kernel(const float* __restrict__ qkv,
                                                          const float* __restrict__ gate_wq,
                                                          float* __restrict__ q_gate) {
    int nb = blockIdx.x, h = blockIdx.y;
    int tid = threadIdx.x;
    __shared__ float pool[96];
    if (tid < 96) {
        float s = 0.f;
        for (int i = 0; i < 64; i++)
            for (int g = 0; g < 4; g++)
                s += qkv[(size_t)(nb * 64 + i) * QKV_N + (h * 4 + g) * 96 + tid];
        pool[tid] = s * (1.f / 256.f);
    }
    __syncthreads();
    float acc = 0.f;
    for (int e = 0; e < 96; e++) acc += pool[e] * gate_wq[e * GHDIM + tid];
    q_gate[(size_t)(nb * NKV + h) * GHDIM + tid] = acc;
}

// ---------------- block gate logits -> softmax -> threshold mask --------------
__global__ __launch_bounds__(64) void blockmask_kernel(const float* __restrict__ q_gate,
                                                       const float* __restrict__ k_gate,
                                                       int* __restrict__ mask) {
    int h = blockIdx.x, qb = blockIdx.y;
    int tid = threadIdx.x;
    __shared__ float logits[32];
    if (tid < 32) {
        if (tid <= qb) {
            float acc = 0.f;
            const float* qg = &q_gate[(size_t)(qb * NKV + h) * GHDIM];
            const float* kg = &k_gate[(size_t)(tid * NKV + h) * GHDIM];
            for (int e = 0; e < GHDIM; e++) acc += qg[e] * kg[e];
            logits[tid] = acc * 0.08838834764831845f;
        } else {
            logits[tid] = -1e30f;
        }
    }
    __syncthreads();
    if (tid < 32) {
        float mx = -1e30f;
        for (int j = 0; j <= qb; j++) mx = fmaxf(mx, logits[j]);
        float sum = 0.f;
        for (int j = 0; j <= qb; j++) sum += __expf(logits[j] - mx);
        float p = (tid <= qb) ? __expf(logits[tid] - mx) / sum : 0.f;
        int m = ((p >= 0.03f) && (tid <= qb)) || (tid == qb);
        mask[(h * NB + qb) * NB + tid] = m;
    }
}

// ---------------- fused RoPE: q -> Qb bf16 (pre-scaled), k -> Kb bf16 [h][s][96]
__global__ __launch_bounds__(256) void rope_qk_kernel(const float* __restrict__ qkv,
                                                      const float* __restrict__ cosb,
                                                      const float* __restrict__ sinb,
                                                      ushort_t* __restrict__ Qb,
                                                      ushort_t* __restrict__ Kb) {
    int idx = blockIdx.x * 256 + threadIdx.x;  // total S*40*48
    int d = idx % 48;
    int tmp = idx / 48;
    int head = tmp % 40;
    int s = tmp / 40;
    float c0 = cosb[s * 96 + d], c1 = cosb[s * 96 + d + 48];
    float s0 = sinb[s * 96 + d], s1 = sinb[s * 96 + d + 48];
    if (head < 32) {
        size_t base = (size_t)s * QKV_N + head * 96;
        float x0 = qkv[base + d], x1 = qkv[base + d + 48];
        size_t ob = (size_t)s * HID + head * 96;
        Qb[ob + d] = f2bf((x0 * c0 - x1 * s0) * SCALE2);
        Qb[ob + d + 48] = f2bf((x1 * c1 + x0 * s1) * SCALE2);
    } else {
        int hh = head - 32;
        size_t base = (size_t)s * QKV_N + HID + hh * 96;
        float x0 = qkv[base + d], x1 = qkv[base + d + 48];
        size_t ob = ((size_t)hh * S_LEN + s) * 96;
        Kb[ob + d] = f2bf(x0 * c0 - x1 * s0);
        Kb[ob + d + 48] = f2bf(x1 * c1 + x0 * s1);
    }
}

// ---------------- V transpose -> Vtb bf16 [NKV][96][S] ------------------------
__global__ __launch_bounds__(256) void transpose_v_kernel(const float* __restrict__ qkv,
                                                          ushort_t* __restrict__ Vtb) {
    __shared__ float Vs[64][97];
    const int ibk = blockIdx.x, h = blockIdx.y;
    const int tid = threadIdx.x;
    {
        int t = tid >> 2, cq = tid & 3;
#pragma unroll
        for (int i = 0; i < 6; ++i) {
            int c = cq * 24 + i * 4;
            const float4 v = *(const float4*)(qkv + (size_t)(ibk * 64 + t) * QKV_N +
                                              HID + 768 + h * 96 + c);
            Vs[t][c] = v.x; Vs[t][c + 1] = v.y; Vs[t][c + 2] = v.z; Vs[t][c + 3] = v.w;
        }
    }
    __syncthreads();
#pragma unroll
    for (int it = 0; it < 3; ++it) {
        int s = tid + it * 256;
        int d = s >> 3, tc = s & 7;
        int4 r;
        r.x = (int)(packbf2(Vs[tc * 8 + 0][d], Vs[tc * 8 + 1][d]));
        r.y = (int)(packbf2(Vs[tc * 8 + 2][d], Vs[tc * 8 + 3][d]));
        r.z = (int)(packbf2(Vs[tc * 8 + 4][d], Vs[tc * 8 + 5][d]));
        r.w = (int)(packbf2(Vs[tc * 8 + 6][d], Vs[tc * 8 + 7][d]));
        *(int4*)(Vtb + ((size_t)h * 96 + d) * S_LEN + ibk * 64 + tc * 8) = r;
    }
}

// ============ MFMA block-sparse flash attention v3 ============================
// S^T = K.Q^T orientation: softmax rows live per-lane (q = lane&15) -> in-lane
// reductions + 2 shuffles. PV as O^T = V^T.P^T via 16x16x16 MFMA whose
// B-layout (k=quad*4+j) matches S^T's C-layout (k=quad*4+r) -> NO P LDS
// round-trip. Async dbuf staging with raw s_barrier + vmcnt(6).
__global__ __launch_bounds__(256) void attn_mfma(const ushort_t* __restrict__ Qb,
                                                 const ushort_t* __restrict__ Kb,
                                                 const ushort_t* __restrict__ Vtb,
                                                 const int* __restrict__ mask,
                                                 ushort_t* __restrict__ out) {
    const int hq = blockIdx.x;
    const int ib = NB - 1 - (int)blockIdx.y;
    const int h = hq >> 2;
    const int tid = threadIdx.x;
    const int lane = tid & 63;
    const int w = tid >> 6;
    const int l15 = lane & 15;
    const int quad = lane >> 4;

    __shared__ ushort_t KsL[2][64 * 96];  // [t][12 chunks, rotated by t&7]
    __shared__ ushort_t VtL[2][96 * 64];  // [d][8 chunks, xor d&7]

    // K-read chunk positions: p = (c + (t&7)) % 12, c = ks*4+quad, t&7 = l15&7
    int pk[3];
    {
        int b0 = quad + (l15 & 7);
#pragma unroll
        for (int ks = 0; ks < 3; ++ks) {
            int p = b0 + ks * 4;
            if (p >= 12) p -= 12;
            if (p >= 12) p -= 12;
            pk[ks] = p;
        }
    }

    bf16x8 qf[3];
    {
        const ushort_t* qp = Qb + (size_t)(ib * 64 + w * 16 + l15) * HID + hq * 96;
#pragma unroll
        for (int ks = 0; ks < 3; ++ks)
            qf[ks] = *(const bf16x8*)(qp + ks * 32 + quad * 8);
    }

    const ushort_t* kbase = Kb + (size_t)h * S_LEN * 96;
    const ushort_t* vbase = Vtb + (size_t)h * 96 * S_LEN;

    unsigned long long bits =
        __ballot((lane <= ib) && (mask[(h * NB + ib) * NB + (lane & 31)] != 0));

    float m_i = -1e30f, l_i = 0.f;   // per-lane: this lane's q-row = w*16+l15
    f32x4 acc_o[6] = {};             // O^T[d=dt*16+quad*4+r][q=l15]

    auto stage = [&](int jb, int buf) {
#pragma unroll
        for (int j = 0; j < 3; ++j) {
            int s = j * 256 + w * 64 + lane;
            int t = (s * 2731) >> 15;       // s / 12
            int cpos = s - t * 12;
            int c = cpos - (t & 7);
            if (c < 0) c += 12;
            gl_lds16(kbase + (size_t)(jb * 64 + t) * 96 + c * 8,
                     &KsL[buf][(j * 256 + w * 64) * 8]);
        }
#pragma unroll
        for (int j = 0; j < 3; ++j) {
            int s = j * 256 + w * 64 + lane;
            int d = s >> 3;
            int tc = (s & 7) ^ (d & 7);
            gl_lds16(vbase + (size_t)d * S_LEN + jb * 64 + tc * 8,
                     &VtL[buf][(j * 256 + w * 64) * 8]);
        }
    };

    int jb = (int)__builtin_ctzll(bits);
    bits &= bits - 1;
    stage(jb, 0);
    int cur = 0;

    while (true) {
        int jn = -1;
        if (bits) {
            jn = (int)__builtin_ctzll(bits);
            bits &= bits - 1;
        }
        if (jn >= 0) {
            stage(jn, cur ^ 1);
            asm volatile("s_waitcnt vmcnt(6)" ::: "memory");  // cur's 6 loads done
        } else {
            asm volatile("s_waitcnt vmcnt(0)" ::: "memory");
        }
        barrier_raw();

        const ushort_t* Kc = KsL[cur];
        const ushort_t* Vc = VtL[cur];

        // S^T = K.Q^T: st[nt] rows = k-pos (nt*16+quad*4+r), cols = q (l15)
        f32x4 st[4] = {};
#pragma unroll
        for (int ks = 0; ks < 3; ++ks)
#pragma unroll
            for (int nt = 0; nt < 4; ++nt) {
                bf16x8 kb = *(const bf16x8*)&Kc[(nt * 16 + l15) * 96 + pk[ks] * 8];
                st[nt] = __builtin_amdgcn_mfma_f32_16x16x32_bf16(kb, qf[ks], st[nt], 0, 0, 0);
            }
        if (jb == ib) {
            int q = w * 16 + l15;
#pragma unroll
            for (int nt = 0; nt < 4; ++nt)
#pragma unroll
                for (int r = 0; r < 4; ++r)
                    if ((nt * 16 + quad * 4 + r) > q) st[nt][r] = -1e30f;
        }
        // in-lane row max over 16 k-values, then 2 shuffles across quads
        float mx = -1e30f;
#pragma unroll
        for (int nt = 0; nt < 4; ++nt)
#pragma unroll
            for (int r = 0; r < 4; ++r) mx = fmaxf(mx, st[nt][r]);
        mx = fmaxf(mx, __shfl_xor(mx, 16));
        mx = fmaxf(mx, __shfl_xor(mx, 32));
        float mnew = fmaxf(m_i, mx);
        float alpha = __builtin_amdgcn_exp2f(m_i - mnew);
        float ps = 0.f;
#pragma unroll
        for (int nt = 0; nt < 4; ++nt)
#pragma unroll
            for (int r = 0; r < 4; ++r) {
                float p = __builtin_amdgcn_exp2f(st[nt][r] - mnew);
                st[nt][r] = p;
                ps += p;
            }
        ps += __shfl_xor(ps, 16);
        ps += __shfl_xor(ps, 32);
        l_i = l_i * alpha + ps;
        m_i = mnew;
#pragma unroll
        for (int t = 0; t < 6; ++t)
#pragma unroll
            for (int r = 0; r < 4; ++r) acc_o[t][r] *= alpha;
        // P^T B-frags (k=quad*4+j matches C-layout k=quad*4+r), in-register
        bf16x4 pf[4];
#pragma unroll
        for (int kblk = 0; kblk < 4; ++kblk) {
            union { bf16x4 v; unsigned u[2]; } pb;
            pb.u[0] = packbf2(st[kblk][0], st[kblk][1]);
            pb.u[1] = packbf2(st[kblk][2], st[kblk][3]);
            pf[kblk] = pb.v;
        }
        // O^T += V^T . P^T via 16x16x16 MFMA; V^T A-frag = ds_read_b64
#pragma unroll
        for (int kblk = 0; kblk < 4; ++kblk) {
            int cchunk = kblk * 2 + (quad >> 1);
            int eoff = (quad & 1) * 4;
#pragma unroll
            for (int dt = 0; dt < 6; ++dt) {
                int d = dt * 16 + l15;
                bf16x4 vf = *(const bf16x4*)&Vc[(d * 8 + (cchunk ^ (d & 7))) * 8 + eoff];
                acc_o[dt] = __builtin_amdgcn_mfma_f32_16x16x16bf16_1k(
                    vf, pf[kblk], acc_o[dt], 0, 0, 0);
            }
        }

        if (jn < 0) break;
        asm volatile("s_waitcnt lgkmcnt(0)" ::: "memory");
        barrier_raw();
        jb = jn;
        cur ^= 1;
    }

    // epilogue: O^T lane holds d = dt*16+quad*4+r, q = l15; pack 4 d per store
    float inv = 1.f / l_i;
    size_t orow = (size_t)(ib * 64 + w * 16 + l15) * HID + hq * 96;
#pragma unroll
    for (int dt = 0; dt < 6; ++dt) {
        int2 pkd;
        pkd.x = (int)packbf2(acc_o[dt][0] * inv, acc_o[dt][1] * inv);
        pkd.y = (int)packbf2(acc_o[dt][2] * inv, acc_o[dt][3] * inv);
        *(int2*)(out + orow + dt * 16 + quad * 4) = pkd;
    }
}

extern "C" void kernel_launch(void* const* d_in, const int* in_sizes, int n_in,
                              void* d_out, int out_size, void* d_ws, size_t ws_size,
                              hipStream_t stream) {
    const float* hidden  = (const float*)d_in[0];
    const float* cosb    = (const float*)d_in[1];
    const float* sinb    = (const float*)d_in[2];
    const float* qkv_w   = (const float*)d_in[3];
    const float* o_w     = (const float*)d_in[4];
    const float* gate_wq = (const float*)d_in[5];
    const float* gate_wk = (const float*)d_in[6];
    float* out = (float*)d_out;

    char* ws = (char*)d_ws;
    float*    qkv   = (float*)ws;                          // 37,748,736 B
    ushort_t* h_bf  = (ushort_t*)(ws + 37748736);          // 12,582,912 B (reused as Qb)
    ushort_t* w1t   = (ushort_t*)(ws + 50331648);          // 28,311,552 B
    ushort_t* attn_out = (ushort_t*)(ws + 78643200);       // 12,582,912 B
    ushort_t* Kb    = (ushort_t*)(ws + 91226112);          //  3,145,728 B
    ushort_t* Vtb   = (ushort_t*)(ws + 95420416);          //  3,145,728 B
    float* k_gate   = (float*)(ws + 98566144);
    float* q_gate   = (float*)(ws + 98697216);
    int*   mask     = (int*)(ws + 98828288);
    ushort_t* Qb    = h_bf;              // alias: h_bf dead after gemm1
    ushort_t* o_wt  = (ushort_t*)qkv;    // alias: qkv dead after rope/transpose_v

    // prep for QKV GEMM
    conv_bf16<<<(S_LEN * HID / 4 + 255) / 256, 256, 0, stream>>>(hidden, h_bf, S_LEN * HID / 4);
    transpose_convert<<<dim3(QKV_N / 64, HID / 64), 256, 0, stream>>>(qkv_w, w1t, HID, QKV_N);
    // 1. QKV projection -> f32 qkv
    gemm_bf16<<<dim3(QKV_N / 128, S_LEN / 128), 256, 0, stream>>>(h_bf, w1t, qkv, S_LEN, QKV_N, HID);
    // 2-4. pooled gates + mask (pre-RoPE, fp32)
    pool_gate_k_kernel<<<dim3(NB, NKV), 128, 0, stream>>>(qkv, gate_wk, k_gate);
    pool_gate_q_kernel<<<dim3(NB, NKV), 128, 0, stream>>>(qkv, gate_wq, q_gate);
    blockmask_kernel<<<dim3(NKV, NB), 64, 0, stream>>>(q_gate, k_gate, mask);
    // 5. RoPE + repack to bf16 attention layouts (Q pre-scaled)
    rope_qk_kernel<<<S_LEN * 40 * 48 / 256, 256, 0, stream>>>(qkv, cosb, sinb, Qb, Kb);
    transpose_v_kernel<<<dim3(NB, NKV), 256, 0, stream>>>(qkv, Vtb);
    // prep O-GEMM weights into qkv space (qkv dead now)
    transpose_convert<<<dim3(HID / 64, HID / 64), 256, 0, stream>>>(o_w, o_wt, HID, HID);
    // 6. block-sparse flash attention -> bf16
    attn_mfma<<<dim3(NHEAD, NB), 256, 0, stream>>>(Qb, Kb, Vtb, mask, attn_out);
    // 7. output projection
    gemm_bf16<<<dim3(HID / 128, S_LEN / 128), 256, 0, stream>>>(attn_out, o_wt, out, S_LEN, HID, HID);
}

// Round 6
// 382.024 us; speedup vs baseline: 1.0835x; 1.0188x over previous
//
#include <hip/hip_runtime.h>
#include <hip/hip_bf16.h>
#include <math.h>

#define S_LEN 2048
#define HID 3072
#define NHEAD 32
#define NKV 8
#define HDIM 96
#define QKV_N 4608   // 32*96 + 2*8*96
#define NB 32        // S/64 blocks
#define GHDIM 128
#define KOFF 3072    // K section start col
#define VOFF 3840    // V section start col

typedef __attribute__((ext_vector_type(8))) short bf16x8;
typedef __attribute__((ext_vector_type(4))) short bf16x4;
typedef __attribute__((ext_vector_type(4))) float f32x4;
typedef unsigned short ushort_t;

// 1/sqrt(96) * log2(e): Q pre-scaled so softmax runs in exp2 domain
#define SCALE2 0.14724444754f

__device__ __forceinline__ unsigned short f2bf(float x) {
    unsigned u = __float_as_uint(x);
    u += 0x7fffu + ((u >> 16) & 1u);
    return (unsigned short)(u >> 16);
}
__device__ __forceinline__ unsigned packbf2(float a, float b) {
    return (unsigned)f2bf(a) | ((unsigned)f2bf(b) << 16);
}
__device__ __forceinline__ float bf2f(ushort_t u) {
    return __uint_as_float(((unsigned)u) << 16);
}

#define GLOBAL_AS __attribute__((address_space(1)))
#define LDS_AS __attribute__((address_space(3)))
__device__ __forceinline__ void gl_lds16(const void* g, void* l) {
    __builtin_amdgcn_global_load_lds((const GLOBAL_AS unsigned int*)g,
                                     (LDS_AS unsigned int*)l, 16, 0, 0);
}
__device__ __forceinline__ void barrier_raw() {
    asm volatile("s_barrier" ::: "memory");
}

// ============ bf16 MFMA GEMM (m97 structure): A[M,K] @ Bt[N,K]^T ============
// mode 0: C f32. mode 1 (QKV): Cbf bf16 [M,N]; K-section cols also f32 -> CfK.
__global__ __launch_bounds__(256, 4) void gemm_bf16(const ushort_t* __restrict__ A,
                                                    const ushort_t* __restrict__ Bt,
                                                    float* __restrict__ C,
                                                    ushort_t* __restrict__ Cbf,
                                                    float* __restrict__ CfK,
                                                    int M, int N, int K, int mode) {
    __shared__ ushort_t As[128 * 64];
    __shared__ ushort_t Bs[128 * 64];
    const int tid = threadIdx.x;
    const int lane = tid & 63;
    const int w = tid >> 6;
    const int wm = (w >> 1) * 64;
    const int wn = (w & 1) * 64;
    const int l15 = lane & 15;
    const int quad = lane >> 4;
    const int m0 = blockIdx.y * 128;
    const int n0 = blockIdx.x * 128;

    f32x4 acc[4][4] = {};

    for (int k0 = 0; k0 < K; k0 += 64) {
        __syncthreads();
#pragma unroll
        for (int j = 0; j < 4; ++j) {
            int s = j * 256 + w * 64 + lane;
            int row = s >> 3;
            int kc = (s & 7) ^ (row & 7);
            gl_lds16(A + (size_t)(m0 + row) * K + k0 + kc * 8,
                     &As[(j * 256 + w * 64) * 8]);
        }
#pragma unroll
        for (int j = 0; j < 4; ++j) {
            int s = j * 256 + w * 64 + lane;
            int row = s >> 3;
            int kc = (s & 7) ^ (row & 7);
            gl_lds16(Bt + (size_t)(n0 + row) * K + k0 + kc * 8,
                     &Bs[(j * 256 + w * 64) * 8]);
        }
        __syncthreads();
        bf16x8 af[2][4], bf[2][4];
#pragma unroll
        for (int mt = 0; mt < 4; ++mt) {
            int row = wm + mt * 16 + l15;
            int rx = row & 7;
#pragma unroll
            for (int ph = 0; ph < 2; ++ph)
                af[ph][mt] = *(const bf16x8*)&As[(row * 8 + ((ph * 4 + quad) ^ rx)) * 8];
        }
#pragma unroll
        for (int nt = 0; nt < 4; ++nt) {
            int row = wn + nt * 16 + l15;
            int rx = row & 7;
#pragma unroll
            for (int ph = 0; ph < 2; ++ph)
                bf[ph][nt] = *(const bf16x8*)&Bs[(row * 8 + ((ph * 4 + quad) ^ rx)) * 8];
        }
#pragma unroll
        for (int ph = 0; ph < 2; ++ph)
#pragma unroll
            for (int mt = 0; mt < 4; ++mt)
#pragma unroll
                for (int nt = 0; nt < 4; ++nt)
                    acc[mt][nt] = __builtin_amdgcn_mfma_f32_16x16x32_bf16(
                        af[ph][mt], bf[ph][nt], acc[mt][nt], 0, 0, 0);
    }
    if (mode == 0) {
#pragma unroll
        for (int mt = 0; mt < 4; ++mt)
#pragma unroll
            for (int nt = 0; nt < 4; ++nt)
#pragma unroll
                for (int r = 0; r < 4; ++r) {
                    int row = m0 + wm + mt * 16 + quad * 4 + r;
                    int col = n0 + wn + nt * 16 + l15;
                    C[(size_t)row * N + col] = acc[mt][nt][r];
                }
    } else {
        const bool isK = (n0 >= KOFF) && (n0 < VOFF);
#pragma unroll
        for (int mt = 0; mt < 4; ++mt)
#pragma unroll
            for (int nt = 0; nt < 4; ++nt)
#pragma unroll
                for (int r = 0; r < 4; ++r) {
                    int row = m0 + wm + mt * 16 + quad * 4 + r;
                    int col = n0 + wn + nt * 16 + l15;
                    Cbf[(size_t)row * N + col] = f2bf(acc[mt][nt][r]);
                    if (isK) CfK[(size_t)row * 768 + col - KOFF] = acc[mt][nt][r];
                }
    }
}

// ---------------- shared bodies for fused prep kernels ------------------------
__device__ __forceinline__ void conv_body(const float* __restrict__ X,
                                          ushort_t* __restrict__ Y, int i) {
    const float4 v = *(const float4*)(X + (size_t)i * 4);
    int2 p;
    p.x = (int)packbf2(v.x, v.y);
    p.y = (int)packbf2(v.z, v.w);
    *(int2*)(Y + (size_t)i * 4) = p;
}

__device__ __forceinline__ void transpose_body(const float* __restrict__ W,
                                               ushort_t* __restrict__ Wt,
                                               int K, int N, int k0, int n0, int tid) {
    __shared__ float Ts[64][65];
    {
        int r = tid >> 2, cq = tid & 3;
#pragma unroll
        for (int i = 0; i < 4; ++i) {
            int c = cq * 16 + i * 4;
            const float4 v = *(const float4*)(W + (size_t)(k0 + r) * N + n0 + c);
            Ts[r][c] = v.x; Ts[r][c + 1] = v.y; Ts[r][c + 2] = v.z; Ts[r][c + 3] = v.w;
        }
    }
    __syncthreads();
#pragma unroll
    for (int it = 0; it < 2; ++it) {
        int n = (tid >> 3) + it * 32;
        int kc = tid & 7;
        int4 r;
        r.x = (int)(packbf2(Ts[kc * 8 + 0][n], Ts[kc * 8 + 1][n]));
        r.y = (int)(packbf2(Ts[kc * 8 + 2][n], Ts[kc * 8 + 3][n]));
        r.z = (int)(packbf2(Ts[kc * 8 + 4][n], Ts[kc * 8 + 5][n]));
        r.w = (int)(packbf2(Ts[kc * 8 + 6][n], Ts[kc * 8 + 7][n]));
        *(int4*)(Wt + (size_t)(n0 + n) * K + k0 + kc * 8) = r;
    }
}

// prep1: hidden f32->bf16 (blocks 0..6143) + qkv_w transpose (blocks 6144..9599)
__global__ __launch_bounds__(256) void prep1(const float* __restrict__ hidden,
                                             ushort_t* __restrict__ h_bf,
                                             const float* __restrict__ qkv_w,
                                             ushort_t* __restrict__ w1t) {
    int id = blockIdx.x;
    int tid = threadIdx.x;
    if (id < 6144) {
        conv_body(hidden, h_bf, id * 256 + tid);
    } else {
        int r = id - 6144;              // 72 x 48
        transpose_body(qkv_w, w1t, HID, QKV_N, (r / 72) * 64, (r % 72) * 64, tid);
    }
}

// prep2: RoPE q/k from bf16 qkv (0..15359) + V transpose (15360..15615)
//        + o_w transpose (15616..17919)
__global__ __launch_bounds__(256) void prep2(const ushort_t* __restrict__ qkv_bf,
                                             const float* __restrict__ cosb,
                                             const float* __restrict__ sinb,
                                             ushort_t* __restrict__ Qb,
                                             ushort_t* __restrict__ Kb,
                                             ushort_t* __restrict__ Vtb,
                                             const float* __restrict__ o_w,
                                             ushort_t* __restrict__ o_wt) {
    int id = blockIdx.x;
    int tid = threadIdx.x;
    if (id < 15360) {
        int idx = id * 256 + tid;   // S*40*48
        int d = idx % 48;
        int tmp = idx / 48;
        int head = tmp % 40;
        int s = tmp / 40;
        float c0 = cosb[s * 96 + d], c1 = cosb[s * 96 + d + 48];
        float s0 = sinb[s * 96 + d], s1 = sinb[s * 96 + d + 48];
        if (head < 32) {
            size_t base = (size_t)s * QKV_N + head * 96;
            float x0 = bf2f(qkv_bf[base + d]), x1 = bf2f(qkv_bf[base + d + 48]);
            size_t ob = (size_t)s * HID + head * 96;
            Qb[ob + d] = f2bf((x0 * c0 - x1 * s0) * SCALE2);
            Qb[ob + d + 48] = f2bf((x1 * c1 + x0 * s1) * SCALE2);
        } else {
            int hh = head - 32;
            size_t base = (size_t)s * QKV_N + KOFF + hh * 96;
            float x0 = bf2f(qkv_bf[base + d]), x1 = bf2f(qkv_bf[base + d + 48]);
            size_t ob = ((size_t)hh * S_LEN + s) * 96;
            Kb[ob + d] = f2bf(x0 * c0 - x1 * s0);
            Kb[ob + d + 48] = f2bf(x1 * c1 + x0 * s1);
        }
    } else if (id < 15616) {
        int r = id - 15360;
        int ibk = r & 31, h = r >> 5;
        __shared__ ushort_t Vs[64][104];   // 208B rows, 16B aligned
        {
            int rr = tid >> 2, seg = tid & 3;
#pragma unroll
            for (int j = 0; j < 3; ++j) {
                int c = seg * 24 + j * 8;
                const int4 v = *(const int4*)(qkv_bf + (size_t)(ibk * 64 + rr) * QKV_N +
                                              VOFF + h * 96 + c);
                *(int4*)&Vs[rr][c] = v;
            }
        }
        __syncthreads();
#pragma unroll
        for (int it = 0; it < 3; ++it) {
            int s = tid + it * 256;       // 768 = 96 d x 8 tc
            int d = s >> 3, tc = s & 7;
            int4 o;
            o.x = (int)Vs[tc * 8 + 0][d] | ((int)Vs[tc * 8 + 1][d] << 16);
            o.y = (int)Vs[tc * 8 + 2][d] | ((int)Vs[tc * 8 + 3][d] << 16);
            o.z = (int)Vs[tc * 8 + 4][d] | ((int)Vs[tc * 8 + 5][d] << 16);
            o.w = (int)Vs[tc * 8 + 6][d] | ((int)Vs[tc * 8 + 7][d] << 16);
            *(int4*)(Vtb + ((size_t)h * 96 + d) * S_LEN + ibk * 64 + tc * 8) = o;
        }
    } else {
        int r = id - 15616;             // 48 x 48
        transpose_body(o_w, o_wt, HID, HID, (r / 48) * 64, (r % 48) * 64, tid);
    }
}

// ---------------- fused pools: k (mean+max, f32) + q (mean, bf16) + gate GEMVs
__global__ __launch_bounds__(256) void pool_gate_kernel(const float* __restrict__ qkvK,
                                                        const ushort_t* __restrict__ qkv_bf,
                                                        const float* __restrict__ gate_wk,
                                                        const float* __restrict__ gate_wq,
                                                        float* __restrict__ k_gate,
                                                        float* __restrict__ q_gate) {
    int nb = blockIdx.x, h = blockIdx.y;
    int tid = threadIdx.x;
    __shared__ float poolk[192];
    __shared__ float poolq[96];
    if (tid < 128) {
        if (tid < 96) {
            float s = 0.f, mx = -1e30f;
            for (int i = 0; i < 64; i++) {
                float v = qkvK[(size_t)(nb * 64 + i) * 768 + h * 96 + tid];
                s += v;
                mx = fmaxf(mx, v);
            }
            poolk[tid] = s * (1.f / 64.f);
            poolk[96 + tid] = mx;
        }
    } else {
        int t2 = tid - 128;
        if (t2 < 96) {
            float s = 0.f;
            for (int i = 0; i < 64; i++)
#pragma unroll
                for (int g = 0; g < 4; g++)
                    s += bf2f(qkv_bf[(size_t)(nb * 64 + i) * QKV_N + (h * 4 + g) * 96 + t2]);
            poolq[t2] = s * (1.f / 256.f);
        }
    }
    __syncthreads();
    if (tid < 128) {
        float acc = 0.f;
        for (int e = 0; e < 192; e++) acc += poolk[e] * gate_wk[e * GHDIM + tid];
        k_gate[(size_t)(nb * NKV + h) * GHDIM + tid] = acc;
    } else {
        int t2 = tid - 128;
        float acc = 0.f;
        for (int e = 0; e < 96; e++) acc += poolq[e] * gate_wq[e * GHDIM + t2];
        q_gate[(size_t)(nb * NKV + h) * GHDIM + t2] = acc;
    }
}

// ---------------- block gate logits -> softmax -> threshold mask --------------
__global__ __launch_bounds__(64) void blockmask_kernel(const float* __restrict__ q_gate,
                                                       const float* __restrict__ k_gate,
                                                       int* __restrict__ mask) {
    int h = blockIdx.x, qb = blockIdx.y;
    int tid = threadIdx.x;
    __shared__ float logits[32];
    if (tid < 32) {
        if (tid <= qb) {
            float acc = 0.f;
            const float* qg = &q_gate[(size_t)(qb * NKV + h) * GHDIM];
            const float* kg = &k_gate[(size_t)(tid * NKV + h) * GHDIM];
            for (int e = 0; e < GHDIM; e++) acc += qg[e] * kg[e];
            logits[tid] = acc * 0.08838834764831845f;
        } else {
            logits[tid] = -1e30f;
        }
    }
    __syncthreads();
    if (tid < 32) {
        float mx = -1e30f;
        for (int j = 0; j <= qb; j++) mx = fmaxf(mx, logits[j]);
        float sum = 0.f;
        for (int j = 0; j <= qb; j++) sum += __expf(logits[j] - mx);
        float p = (tid <= qb) ? __expf(logits[tid] - mx) / sum : 0.f;
        int m = ((p >= 0.03f) && (tid <= qb)) || (tid == qb);
        mask[(h * NB + qb) * NB + tid] = m;
    }
}

// ============ MFMA block-sparse flash attention v3 (unchanged from R5) ========
__global__ __launch_bounds__(256) void attn_mfma(const ushort_t* __restrict__ Qb,
                                                 const ushort_t* __restrict__ Kb,
                                                 const ushort_t* __restrict__ Vtb,
                                                 const int* __restrict__ mask,
                                                 ushort_t* __restrict__ out) {
    const int hq = blockIdx.x;
    const int ib = NB - 1 - (int)blockIdx.y;
    const int h = hq >> 2;
    const int tid = threadIdx.x;
    const int lane = tid & 63;
    const int w = tid >> 6;
    const int l15 = lane & 15;
    const int quad = lane >> 4;

    __shared__ ushort_t KsL[2][64 * 96];
    __shared__ ushort_t VtL[2][96 * 64];

    int pk[3];
    {
        int b0 = quad + (l15 & 7);
#pragma unroll
        for (int ks = 0; ks < 3; ++ks) {
            int p = b0 + ks * 4;
            if (p >= 12) p -= 12;
            if (p >= 12) p -= 12;
            pk[ks] = p;
        }
    }

    bf16x8 qf[3];
    {
        const ushort_t* qp = Qb + (size_t)(ib * 64 + w * 16 + l15) * HID + hq * 96;
#pragma unroll
        for (int ks = 0; ks < 3; ++ks)
            qf[ks] = *(const bf16x8*)(qp + ks * 32 + quad * 8);
    }

    const ushort_t* kbase = Kb + (size_t)h * S_LEN * 96;
    const ushort_t* vbase = Vtb + (size_t)h * 96 * S_LEN;

    unsigned long long bits =
        __ballot((lane <= ib) && (mask[(h * NB + ib) * NB + (lane & 31)] != 0));

    float m_i = -1e30f, l_i = 0.f;
    f32x4 acc_o[6] = {};

    auto stage = [&](int jb, int buf) {
#pragma unroll
        for (int j = 0; j < 3; ++j) {
            int s = j * 256 + w * 64 + lane;
            int t = (s * 2731) >> 15;
            int cpos = s - t * 12;
            int c = cpos - (t & 7);
            if (c < 0) c += 12;
            gl_lds16(kbase + (size_t)(jb * 64 + t) * 96 + c * 8,
                     &KsL[buf][(j * 256 + w * 64) * 8]);
        }
#pragma unroll
        for (int j = 0; j < 3; ++j) {
            int s = j * 256 + w * 64 + lane;
            int d = s >> 3;
            int tc = (s & 7) ^ (d & 7);
            gl_lds16(vbase + (size_t)d * S_LEN + jb * 64 + tc * 8,
                     &VtL[buf][(j * 256 + w * 64) * 8]);
        }
    };

    int jb = (int)__builtin_ctzll(bits);
    bits &= bits - 1;
    stage(jb, 0);
    int cur = 0;

    while (true) {
        int jn = -1;
        if (bits) {
            jn = (int)__builtin_ctzll(bits);
            bits &= bits - 1;
        }
        if (jn >= 0) {
            stage(jn, cur ^ 1);
            asm volatile("s_waitcnt vmcnt(6)" ::: "memory");
        } else {
            asm volatile("s_waitcnt vmcnt(0)" ::: "memory");
        }
        barrier_raw();

        const ushort_t* Kc = KsL[cur];
        const ushort_t* Vc = VtL[cur];

        f32x4 st[4] = {};
#pragma unroll
        for (int ks = 0; ks < 3; ++ks)
#pragma unroll
            for (int nt = 0; nt < 4; ++nt) {
                bf16x8 kb = *(const bf16x8*)&Kc[(nt * 16 + l15) * 96 + pk[ks] * 8];
                st[nt] = __builtin_amdgcn_mfma_f32_16x16x32_bf16(kb, qf[ks], st[nt], 0, 0, 0);
            }
        if (jb == ib) {
            int q = w * 16 + l15;
#pragma unroll
            for (int nt = 0; nt < 4; ++nt)
#pragma unroll
                for (int r = 0; r < 4; ++r)
                    if ((nt * 16 + quad * 4 + r) > q) st[nt][r] = -1e30f;
        }
        float mx = -1e30f;
#pragma unroll
        for (int nt = 0; nt < 4; ++nt)
#pragma unroll
            for (int r = 0; r < 4; ++r) mx = fmaxf(mx, st[nt][r]);
        mx = fmaxf(mx, __shfl_xor(mx, 16));
        mx = fmaxf(mx, __shfl_xor(mx, 32));
        float mnew = fmaxf(m_i, mx);
        float alpha = __builtin_amdgcn_exp2f(m_i - mnew);
        float ps = 0.f;
#pragma unroll
        for (int nt = 0; nt < 4; ++nt)
#pragma unroll
            for (int r = 0; r < 4; ++r) {
                float p = __builtin_amdgcn_exp2f(st[nt][r] - mnew);
                st[nt][r] = p;
                ps += p;
            }
        ps += __shfl_xor(ps, 16);
        ps += __shfl_xor(ps, 32);
        l_i = l_i * alpha + ps;
        m_i = mnew;
#pragma unroll
        for (int t = 0; t < 6; ++t)
#pragma unroll
            for (int r = 0; r < 4; ++r) acc_o[t][r] *= alpha;
        bf16x4 pf[4];
#pragma unroll
        for (int kblk = 0; kblk < 4; ++kblk) {
            union { bf16x4 v; unsigned u[2]; } pb;
            pb.u[0] = packbf2(st[kblk][0], st[kblk][1]);
            pb.u[1] = packbf2(st[kblk][2], st[kblk][3]);
            pf[kblk] = pb.v;
        }
#pragma unroll
        for (int kblk = 0; kblk < 4; ++kblk) {
            int cchunk = kblk * 2 + (quad >> 1);
            int eoff = (quad & 1) * 4;
#pragma unroll
            for (int dt = 0; dt < 6; ++dt) {
                int d = dt * 16 + l15;
                bf16x4 vf = *(const bf16x4*)&Vc[(d * 8 + (cchunk ^ (d & 7))) * 8 + eoff];
                acc_o[dt] = __builtin_amdgcn_mfma_f32_16x16x16bf16_1k(
                    vf, pf[kblk], acc_o[dt], 0, 0, 0);
            }
        }

        if (jn < 0) break;
        asm volatile("s_waitcnt lgkmcnt(0)" ::: "memory");
        barrier_raw();
        jb = jn;
        cur ^= 1;
    }

    float inv = 1.f / l_i;
    size_t orow = (size_t)(ib * 64 + w * 16 + l15) * HID + hq * 96;
#pragma unroll
    for (int dt = 0; dt < 6; ++dt) {
        int2 pkd;
        pkd.x = (int)packbf2(acc_o[dt][0] * inv, acc_o[dt][1] * inv);
        pkd.y = (int)packbf2(acc_o[dt][2] * inv, acc_o[dt][3] * inv);
        *(int2*)(out + orow + dt * 16 + quad * 4) = pkd;
    }
}

extern "C" void kernel_launch(void* const* d_in, const int* in_sizes, int n_in,
                              void* d_out, int out_size, void* d_ws, size_t ws_size,
                              hipStream_t stream) {
    const float* hidden  = (const float*)d_in[0];
    const float* cosb    = (const float*)d_in[1];
    const float* sinb    = (const float*)d_in[2];
    const float* qkv_w   = (const float*)d_in[3];
    const float* o_w     = (const float*)d_in[4];
    const float* gate_wq = (const float*)d_in[5];
    const float* gate_wk = (const float*)d_in[6];
    float* out = (float*)d_out;

    char* ws = (char*)d_ws;
    ushort_t* qkv_bf   = (ushort_t*)ws;                    // 18,874,368 B
    float*    qkv_f32K = (float*)(ws + 18874368);          //  6,291,456 B
    ushort_t* h_bf     = (ushort_t*)(ws + 25165824);       // 12,582,912 B (reused as Qb)
    ushort_t* w1t      = (ushort_t*)(ws + 37748736);       // 28,311,552 B (reused as o_wt)
    ushort_t* attn_out = (ushort_t*)(ws + 66060288);       // 12,582,912 B
    ushort_t* Kb       = (ushort_t*)(ws + 78643200);       //  3,145,728 B
    ushort_t* Vtb      = (ushort_t*)(ws + 81788928);       //  3,145,728 B
    float*    k_gate   = (float*)(ws + 84934656);          //    131,072 B
    float*    q_gate   = (float*)(ws + 85065728);          //    131,072 B
    int*      mask     = (int*)(ws + 85196800);            //     32,768 B
    ushort_t* Qb   = h_bf;            // alias: h_bf dead after gemm1
    ushort_t* o_wt = w1t;             // alias: w1t dead after gemm1

    // prep1: hidden->bf16 + qkv_w transpose (fused, independent blocks)
    prep1<<<9600, 256, 0, stream>>>(hidden, h_bf, qkv_w, w1t);
    // 1. QKV projection -> bf16 qkv (+ f32 K-section for exact gate numerics)
    gemm_bf16<<<dim3(QKV_N / 128, S_LEN / 128), 256, 0, stream>>>(
        h_bf, w1t, nullptr, qkv_bf, qkv_f32K, S_LEN, QKV_N, HID, 1);
    // 2. fused pools + gate GEMVs
    pool_gate_kernel<<<dim3(NB, NKV), 256, 0, stream>>>(qkv_f32K, qkv_bf,
                                                        gate_wk, gate_wq, k_gate, q_gate);
    // 3. block mask
    blockmask_kernel<<<dim3(NKV, NB), 64, 0, stream>>>(q_gate, k_gate, mask);
    // 4. prep2: RoPE q/k + V transpose + o_w transpose (fused)
    prep2<<<17920, 256, 0, stream>>>(qkv_bf, cosb, sinb, Qb, Kb, Vtb, o_w, o_wt);
    // 5. block-sparse flash attention -> bf16
    attn_mfma<<<dim3(NHEAD, NB), 256, 0, stream>>>(Qb, Kb, Vtb, mask, attn_out);
    // 6. output projection -> f32 out
    gemm_bf16<<<dim3(HID / 128, S_LEN / 128), 256, 0, stream>>>(
        attn_out, o_wt, out, nullptr, nullptr, S_LEN, HID, HID, 0);
}